// Round 1
// baseline (155.523 us; speedup 1.0000x reference)
//
#include <hip/hip_runtime.h>

#define BB 16
#define CC 2
#define TT 1000
#define FF 257
#define NCHAIN (BB * CC * FF)                       // 8224
#define RES_ELEMS ((size_t)BB * CC * TT * FF * 2)   // 16,448,000

#define CPB 8           // chains per block (== waves per block)
#define KCH 64          // chunks per chain
#define LCH 16          // timesteps per chunk (64*16 = 1024 >= 1000, tail predicated)

// block = (8, 64) = 512 threads = 8 waves; grid = 8224/8 = 1028 blocks (4/CU)
// launch_bounds(512, 8): force VGPR <= 64 so 8 waves/SIMD -> 32 waves/CU resident
__global__ __launch_bounds__(512, 8) void fnorm_kernel(
    const float* __restrict__ input,
    const float* __restrict__ weights,
    const float* __restrict__ bias,
    const float* __restrict__ alpha,
    const float* __restrict__ s1,
    float* __restrict__ out)
{
    const int tx = threadIdx.x;          // chain within block (0..7)
    const int k  = threadIdx.y;          // chunk index (0..63)
    const int chain = blockIdx.x * CPB + tx;   // always < 8224 (1028*8 exact)

    const int f  = chain % FF;
    const int bc = chain / FF;
    const int c  = bc % CC;
    const int cf = c * FF + f;

    const float2* __restrict__ in2 = (const float2*)input + (size_t)bc * (TT * FF) + f;
    float2* __restrict__ out2      = (float2*)out        + (size_t)bc * (TT * FF) + f;

    const float av = 1.0f / (1.0f + __expf(-alpha[cf]));
    const float om = 1.0f - av;
    const float w  = weights[cf];
    const float bi = bias[cf];

    const int t0  = k * LCH;
    const int rem = TT - t0;
    const int n   = rem < LCH ? (rem < 0 ? 0 : rem) : LCH;   // valid steps this chunk

    // Phase A: load chunk into registers (32 VGPR buffer, 16 independent loads
    // in flight per thread), compute chunk-local scan-from-zero end value e and
    // decay p = om^n.
    float2 x[LCH];
    #pragma unroll
    for (int t = 0; t < LCH; ++t)
        if (t < n) x[t] = in2[(size_t)(t0 + t) * FF];

    float s = 0.0f;
    float p = 1.0f;
    #pragma unroll
    for (int t = 0; t < LCH; ++t) {
        if (t < n) {
            float2 v = x[t];
            float d2 = fmaf(v.x, v.x, v.y * v.y);
            s = fmaf(d2, av, s * om);
            p *= om;
        }
    }

    // Fix-up: wave-parallel affine scan. Wave wv owns chain (blockIdx*CPB + wv);
    // lane ln owns chunk ln of that chain. Compose affine maps S -> p*S + e.
    __shared__ float p_s[KCH][CPB + 1];   // +1 pad: conflict-free transposed read
    __shared__ float e_s[KCH][CPB + 1];
    __shared__ float i_s[KCH][CPB + 1];
    p_s[k][tx] = p;
    e_s[k][tx] = s;
    __syncthreads();
    {
        const int tid = k * CPB + tx;
        const int wv  = tid >> 6;    // 0..7 == chain within block
        const int ln  = tid & 63;    // 0..63 == chunk
        float pp = p_s[ln][wv];
        float ee = e_s[ln][wv];
        #pragma unroll
        for (int d = 1; d < 64; d <<= 1) {
            float pu = __shfl_up(pp, d, 64);
            float eu = __shfl_up(ee, d, 64);
            if (ln >= d) { ee = fmaf(pp, eu, ee); pp *= pu; }
        }
        const float S0 = s1[blockIdx.x * CPB + wv];
        float Sin = fmaf(pp, S0, ee);          // inclusive state after chunk ln
        float Sex = __shfl_up(Sin, 1, 64);     // exclusive = init state for chunk ln
        if (ln == 0) Sex = S0;
        i_s[ln][wv] = Sex;
        if (ln == 63) out[RES_ELEMS + (size_t)(blockIdx.x * CPB + wv)] = Sin;  // s_last
    }
    __syncthreads();

    // Phase B: rescan chunk from registers with correct initial state.
    s = i_s[k][tx];
    #pragma unroll
    for (int t = 0; t < LCH; ++t) {
        if (t < n) {
            float2 v = x[t];
            float d2 = fmaf(v.x, v.x, v.y * v.y);
            s = fmaf(d2, av, s * om);
            float inv = __frsqrt_rn(s + 1e-16f) * w;
            float2 y;
            y.x = fmaf(v.x, inv, bi);
            y.y = fmaf(v.y, inv, bi);
            out2[(size_t)(t0 + t) * FF] = y;
        }
    }
}

extern "C" void kernel_launch(void* const* d_in, const int* in_sizes, int n_in,
                              void* d_out, int out_size, void* d_ws, size_t ws_size,
                              hipStream_t stream) {
    const float* input   = (const float*)d_in[0];
    const float* weights = (const float*)d_in[1];
    const float* bias    = (const float*)d_in[2];
    const float* alpha   = (const float*)d_in[3];
    const float* s1      = (const float*)d_in[4];
    float* out = (float*)d_out;

    dim3 block(CPB, KCH);               // 512 threads = 8 waves
    dim3 grid(NCHAIN / CPB);            // 1028 blocks
    hipLaunchKernelGGL(fnorm_kernel, grid, block, 0, stream,
                       input, weights, bias, alpha, s1, out);
}

// Round 3
// 136.283 us; speedup vs baseline: 1.1412x; 1.1412x over previous
//
#include <hip/hip_runtime.h>

#define BB 16
#define CC 2
#define TT 1000
#define FF 257
#define NCHAIN (BB * CC * FF)                       // 8224
#define RES_ELEMS ((size_t)BB * CC * TT * FF * 2)   // 16,448,000

#define CPB 32          // chains per block (== threadIdx.x extent)
#define KCH 32          // chunks per chain
#define LCH 32          // timesteps per chunk (32*32 = 1024 >= 1000, tail predicated)

// block = (32, 32) = 1024 threads = 16 waves; grid = 8224/32 = 257 blocks (1/CU)
// launch_bounds(1024, 4): VGPR cap 128 — x[32] buffer (64 VGPR) + overhead fits,
// so Phase B MUST NOT rematerialize global loads (round-1 failure mode).
__global__ __launch_bounds__(1024, 4) void fnorm_kernel(
    const float* __restrict__ input,
    const float* __restrict__ weights,
    const float* __restrict__ bias,
    const float* __restrict__ alpha,
    const float* __restrict__ s1,
    float* __restrict__ out)
{
    const int tx = threadIdx.x;          // chain within block (0..31)
    const int k  = threadIdx.y;          // chunk index (0..31)
    const int chain = blockIdx.x * CPB + tx;   // 257*32 = 8224 exact

    const int f  = chain % FF;
    const int bc = chain / FF;
    const int c  = bc % CC;
    const int cf = c * FF + f;

    const float2* __restrict__ in2 = (const float2*)input + (size_t)bc * (TT * FF) + f;
    float2* __restrict__ out2      = (float2*)out        + (size_t)bc * (TT * FF) + f;

    const float av = 1.0f / (1.0f + __expf(-alpha[cf]));
    const float om = 1.0f - av;
    const float w  = weights[cf];
    const float bi = bias[cf];

    const int t0  = k * LCH;
    const int rem = TT - t0;                                 // >= 8 always
    const int n   = rem < LCH ? rem : LCH;

    // Phase A: load chunk into registers. A 32-lane row (fixed k) covers 32
    // consecutive chains -> 256 B contiguous per half-wave segment.
    float2 x[LCH];
    #pragma unroll
    for (int t = 0; t < LCH; ++t)
        if (t < n) x[t] = in2[(size_t)(t0 + t) * FF];

    float s = 0.0f;
    float p = 1.0f;
    #pragma unroll
    for (int t = 0; t < LCH; ++t) {
        if (t < n) {
            float2 v = x[t];
            float d2 = fmaf(v.x, v.x, v.y * v.y);
            s = fmaf(d2, av, s * om);
            p *= om;
        }
    }

    // Fix-up: wave-parallel affine scan over chunks. Remap: each 32-lane group
    // owns one chain, lane-within-group = chunk. Compose maps S -> p*S + e.
    __shared__ float p_s[KCH][CPB + 1];   // +1 pad: conflict-free transposed access
    __shared__ float e_s[KCH][CPB + 1];
    __shared__ float i_s[KCH][CPB + 1];
    p_s[k][tx] = p;
    e_s[k][tx] = s;
    __syncthreads();
    {
        const int tid = tx + k * CPB;
        const int ln  = tid & 63;
        const int ch  = (tid >> 6) * 2 + (ln >> 5);   // chain 0..31
        const int ck  = ln & 31;                      // chunk 0..31
        float pp = p_s[ck][ch];
        float ee = e_s[ck][ch];
        #pragma unroll
        for (int d = 1; d < 32; d <<= 1) {
            float pu = __shfl_up(pp, d, 32);
            float eu = __shfl_up(ee, d, 32);
            if (ck >= d) { ee = fmaf(pp, eu, ee); pp *= pu; }
        }
        const float S0 = s1[blockIdx.x * CPB + ch];
        float Sin = fmaf(pp, S0, ee);          // inclusive state after chunk ck
        float Sex = __shfl_up(Sin, 1, 32);     // exclusive = init state for chunk ck
        if (ck == 0) Sex = S0;
        i_s[ck][ch] = Sex;
        if (ck == KCH - 1)
            out[RES_ELEMS + (size_t)(blockIdx.x * CPB + ch)] = Sin;  // s_last
    }
    __syncthreads();

    // Phase B: rescan chunk from registers with correct initial state.
    s = i_s[k][tx];
    #pragma unroll
    for (int t = 0; t < LCH; ++t) {
        if (t < n) {
            float2 v = x[t];
            float d2 = fmaf(v.x, v.x, v.y * v.y);
            s = fmaf(d2, av, s * om);
            float inv = __frsqrt_rn(s + 1e-16f) * w;
            float2 y;
            y.x = fmaf(v.x, inv, bi);
            y.y = fmaf(v.y, inv, bi);
            out2[(size_t)(t0 + t) * FF] = y;
        }
    }
}

extern "C" void kernel_launch(void* const* d_in, const int* in_sizes, int n_in,
                              void* d_out, int out_size, void* d_ws, size_t ws_size,
                              hipStream_t stream) {
    const float* input   = (const float*)d_in[0];
    const float* weights = (const float*)d_in[1];
    const float* bias    = (const float*)d_in[2];
    const float* alpha   = (const float*)d_in[3];
    const float* s1      = (const float*)d_in[4];
    float* out = (float*)d_out;

    dim3 block(CPB, KCH);               // 1024 threads = 16 waves
    dim3 grid(NCHAIN / CPB);            // 257 blocks
    hipLaunchKernelGGL(fnorm_kernel, grid, block, 0, stream,
                       input, weights, bias, alpha, s1, out);
}